// Round 4
// baseline (253.433 us; speedup 1.0000x reference)
//
#include <hip/hip_runtime.h>

// KAN-PINN forward, MI355X — round 4.
// Fused to 2 kernels (network is pointwise in n):
//   K1 = layer0 (per-block recompute into LDS) + layer1 (+ side: B1c2 = C2L*B1_2, out = b_out)
//   K2 = layer2 + output head (block partial -> one atomicAdd per point per block)
// tanh via exp2 + INT-MAGIC reciprocal (2 Newton) instead of v_rcp:
//   saves 1 trans (16 cyc) for 5 full-rate VALU (10 cyc) per element.

#define C2L 2.88539008177792681472f  // 2*log2(e)

__device__ __forceinline__ float rcp_nr(float d) {
  // 1/d for d in [1, ~1e30): int-magic seed (~4% err) + 2 Newton -> ~3e-6 rel
  float r = __int_as_float(0x7EF311C2 - __float_as_int(d));
  r = r * fmaf(-d, r, 2.0f);
  r = r * fmaf(-d, r, 2.0f);
  return r;
}

__device__ __forceinline__ float tanh_fast(float z) {
  // tanh(z) = 1 - 2/(1+exp2(C2L*z))
  float e = __builtin_amdgcn_exp2f(z * C2L);
  float s = rcp_nr(1.0f + e);
  return fmaf(s, -2.0f, 1.0f);
}

// ---------------- K1: layer0 + layer1 ----------------
// grid (128, 16), block 256 (4 waves). bx = point-group (64 pts, lane = point),
// by*4+wave = j of layer1. Phase A recomputes layer0 into LDS (6% extra work).
__global__ __launch_bounds__(256, 8) void kan_fused1(
    const float* __restrict__ x, const float* __restrict__ t,
    const float* __restrict__ W1_0, const float* __restrict__ B1_0,  // (64,2,8)
    const float* __restrict__ W2_0, const float* __restrict__ B2_0,  // (64,2,8),(64,2)
    const float* __restrict__ W1_1, const float* __restrict__ B1_1,  // (64,64,8)
    const float* __restrict__ W2_1, const float* __restrict__ B2_1,  // (64,64,8),(64,64)
    const float* __restrict__ B1_2,                                  // (64,64,8) src
    const float* __restrict__ bout,
    float* __restrict__ hB,     // [64][8192], = C2L * h1
    float* __restrict__ B1c2,   // (64,64,8) = C2L * B1_2
    float* __restrict__ out)    // (8192,) initialized to b_out here
{
  __shared__ float hs[64][64];           // h0 (unscaled tanh), 16 KB
  const int tid  = threadIdx.x;
  const int lane = tid & 63;
  const int wave = __builtin_amdgcn_readfirstlane(tid >> 6);
  const int bx = blockIdx.x, by = blockIdx.y;
  const int n = bx * 64 + lane;

  // side tasks (by==0 blocks only): scale B1_2 for K2; init out
  if (by == 0) {
    const int idx = bx * 256 + tid;
    B1c2[idx] = B1_2[idx] * C2L;
    if (tid < 64) out[bx * 64 + tid] = bout[0];
  }

  // ---- Phase A: layer0 for this block's 64 points ----
  const float hx = x[n], ht = t[n];
  for (int q = 0; q < 16; ++q) {
    const int i = wave * 16 + q;                 // layer0 output neuron
    float a0 = B2_0[i * 2 + 0];
    float a1 = B2_0[i * 2 + 1];
#pragma unroll
    for (int k = 0; k < 8; ++k) {
      float z0 = fmaf(hx, W1_0[i * 16 + k], B1_0[i * 16 + k]);
      a0 = fmaf(W2_0[i * 16 + k], tanh_fast(z0), a0);
      float z1 = fmaf(ht, W1_0[i * 16 + 8 + k], B1_0[i * 16 + 8 + k]);
      a1 = fmaf(W2_0[i * 16 + 8 + k], tanh_fast(z1), a1);
    }
    hs[i][lane] = tanh_fast(a0 + a1);            // h0, unscaled
  }
  __syncthreads();

  // ---- Phase B: layer1, one j per wave ----
  const int j = by * 4 + wave;                   // wave-uniform
  const float* __restrict__ w1p = W1_1 + j * 512;
  const float* __restrict__ b1p = B1_1 + j * 512;
  const float* __restrict__ w2p = W2_1 + j * 512;

  // S = sum(W2 row) + sum(B2 row): lane-parallel + shfl reduce
  float sp = B2_1[j * 64 + lane];
  {
    const float4* w2v = (const float4*)w2p;
    float4 va = w2v[lane * 2 + 0];
    float4 vb = w2v[lane * 2 + 1];
    sp += (va.x + va.y) + (va.z + va.w) + (vb.x + vb.y) + (vb.z + vb.w);
  }
#pragma unroll
  for (int off = 32; off; off >>= 1) sp += __shfl_xor(sp, off);
  const float S = sp;

  float acc0 = 0.f, acc1 = 0.f, acc2 = 0.f, acc3 = 0.f;
  for (int i = 0; i < 64; ++i) {
    const float hi = hs[i][lane];
    const int base = i * 8;
#pragma unroll
    for (int k = 0; k < 8; k += 4) {
      float z0 = fmaf(hi, w1p[base + k + 0], b1p[base + k + 0]);
      float z1 = fmaf(hi, w1p[base + k + 1], b1p[base + k + 1]);
      float z2 = fmaf(hi, w1p[base + k + 2], b1p[base + k + 2]);
      float z3 = fmaf(hi, w1p[base + k + 3], b1p[base + k + 3]);
      float s0 = rcp_nr(1.0f + __builtin_amdgcn_exp2f(z0 * C2L));
      float s1 = rcp_nr(1.0f + __builtin_amdgcn_exp2f(z1 * C2L));
      float s2 = rcp_nr(1.0f + __builtin_amdgcn_exp2f(z2 * C2L));
      float s3 = rcp_nr(1.0f + __builtin_amdgcn_exp2f(z3 * C2L));
      acc0 = fmaf(w2p[base + k + 0], s0, acc0);
      acc1 = fmaf(w2p[base + k + 1], s1, acc1);
      acc2 = fmaf(w2p[base + k + 2], s2, acc2);
      acc3 = fmaf(w2p[base + k + 3], s3, acc3);
    }
  }

  const float y = S - 2.f * ((acc0 + acc1) + (acc2 + acc3));
  const float e = __builtin_amdgcn_exp2f(y * C2L);
  const float r = __builtin_amdgcn_rcpf(1.0f + e);
  hB[j * 8192 + n] = fmaf(r, -2.f * C2L, C2L);   // C2L * tanh(y) for K2
}

// ---------------- K2: layer2 + output head ----------------
// grid (128, 16), block 256 (4 waves). hB is pre-scaled by C2L; B1c2 pre-scaled.
__global__ __launch_bounds__(256, 8) void kan_fused2(
    const float* __restrict__ hB,    // [64][8192] = C2L * h1
    const float* __restrict__ W1_2,  // (64,64,8)
    const float* __restrict__ B1c2,  // (64,64,8) = C2L * B1_2
    const float* __restrict__ W2_2,  // (64,64,8)
    const float* __restrict__ B2_2,  // (64,64)
    const float* __restrict__ Wout,  // (1,64)
    float* __restrict__ out)         // (8192,) += partials
{
  __shared__ float hs[64][64];       // 16 KB
  __shared__ float red[4][64];
  const int tid  = threadIdx.x;
  const int lane = tid & 63;
  const int wave = __builtin_amdgcn_readfirstlane(tid >> 6);
  const int bx = blockIdx.x, by = blockIdx.y;
  const int n = bx * 64 + lane;

#pragma unroll
  for (int rr = 0; rr < 16; ++rr) {
    const int i = rr * 4 + wave;
    hs[i][lane] = hB[i * 8192 + n];
  }
  __syncthreads();

  const int j = by * 4 + wave;
  const float* __restrict__ w1p = W1_2 + j * 512;
  const float* __restrict__ b1p = B1c2 + j * 512;
  const float* __restrict__ w2p = W2_2 + j * 512;

  float sp = B2_2[j * 64 + lane];
  {
    const float4* w2v = (const float4*)w2p;
    float4 va = w2v[lane * 2 + 0];
    float4 vb = w2v[lane * 2 + 1];
    sp += (va.x + va.y) + (va.z + va.w) + (vb.x + vb.y) + (vb.z + vb.w);
  }
#pragma unroll
  for (int off = 32; off; off >>= 1) sp += __shfl_xor(sp, off);
  const float S = sp;

  float acc0 = 0.f, acc1 = 0.f, acc2 = 0.f, acc3 = 0.f;
  for (int i = 0; i < 64; ++i) {
    const float hc = hs[i][lane];              // C2L * h
    const int base = i * 8;
#pragma unroll
    for (int k = 0; k < 8; k += 4) {
      float zc0 = fmaf(hc, w1p[base + k + 0], b1p[base + k + 0]);
      float zc1 = fmaf(hc, w1p[base + k + 1], b1p[base + k + 1]);
      float zc2 = fmaf(hc, w1p[base + k + 2], b1p[base + k + 2]);
      float zc3 = fmaf(hc, w1p[base + k + 3], b1p[base + k + 3]);
      float s0 = rcp_nr(1.0f + __builtin_amdgcn_exp2f(zc0));
      float s1 = rcp_nr(1.0f + __builtin_amdgcn_exp2f(zc1));
      float s2 = rcp_nr(1.0f + __builtin_amdgcn_exp2f(zc2));
      float s3 = rcp_nr(1.0f + __builtin_amdgcn_exp2f(zc3));
      acc0 = fmaf(w2p[base + k + 0], s0, acc0);
      acc1 = fmaf(w2p[base + k + 1], s1, acc1);
      acc2 = fmaf(w2p[base + k + 2], s2, acc2);
      acc3 = fmaf(w2p[base + k + 3], s3, acc3);
    }
  }

  const float y = S - 2.f * ((acc0 + acc1) + (acc2 + acc3));
  const float e = __builtin_amdgcn_exp2f(y * C2L);
  const float r = __builtin_amdgcn_rcpf(1.0f + e);
  const float h2 = fmaf(r, -2.f, 1.f);         // tanh(y), unscaled

  red[wave][lane] = h2 * Wout[j];
  __syncthreads();
  if (wave == 0) {
    const float pblk = (red[0][lane] + red[1][lane]) + (red[2][lane] + red[3][lane]);
    atomicAdd(&out[n], pblk);
  }
}

extern "C" void kernel_launch(void* const* d_in, const int* in_sizes, int n_in,
                              void* d_out, int out_size, void* d_ws, size_t ws_size,
                              hipStream_t stream) {
  const float* x    = (const float*)d_in[0];
  const float* t    = (const float*)d_in[1];
  const float* W1_0 = (const float*)d_in[2];
  const float* B1_0 = (const float*)d_in[3];
  const float* W2_0 = (const float*)d_in[4];
  const float* B2_0 = (const float*)d_in[5];
  const float* W1_1 = (const float*)d_in[6];
  const float* B1_1 = (const float*)d_in[7];
  const float* W2_1 = (const float*)d_in[8];
  const float* B2_1 = (const float*)d_in[9];
  const float* W1_2 = (const float*)d_in[10];
  const float* B1_2 = (const float*)d_in[11];
  const float* W2_2 = (const float*)d_in[12];
  const float* B2_2 = (const float*)d_in[13];
  const float* Wout = (const float*)d_in[14];
  const float* bout = (const float*)d_in[15];
  float* out = (float*)d_out;

  float* hB   = (float*)d_ws;          // [64][8192] = 2 MB
  float* B1c2 = hB + 64 * 8192;        // 32768 floats

  kan_fused1<<<dim3(128, 16), 256, 0, stream>>>(
      x, t, W1_0, B1_0, W2_0, B2_0, W1_1, B1_1, W2_1, B2_1, B1_2, bout,
      hB, B1c2, out);
  kan_fused2<<<dim3(128, 16), 256, 0, stream>>>(
      hB, W1_2, B1c2, W2_2, B2_2, Wout, out);
}

// Round 5
// 207.050 us; speedup vs baseline: 1.2240x; 1.2240x over previous
//
#include <hip/hip_runtime.h>

// KAN-PINN forward, MI355X — round 5.
// 3 kernels, no recompute (r4's 16x layer0 replication reverted):
//   K0 = layer0 (grid 128x4) + side-writes: B1c1/B1c2 = C2L*B1, out = b_out
//   K1 = layer1, INT-MAGIC+NR reciprocal   (A/B arm 1)
//   K2 = layer2 + output head (atomicAdd), HARDWARE v_rcp (A/B arm 2)
// K1 vs K2 isolates the recip implementation (same work shape, K2 +head).

#define C2L 2.88539008177792681472f  // 2*log2(e)

__device__ __forceinline__ float rcp_nr(float d) {
  // 1/d, d in [1, ~1e30): int-magic seed + 2 Newton -> ~6e-6 rel err
  float r = __int_as_float(0x7EF311C2 - __float_as_int(d));
  r = r * fmaf(-d, r, 2.0f);
  r = r * fmaf(-d, r, 2.0f);
  return r;
}

__device__ __forceinline__ float tanh_hw(float z) {
  // tanh(z) = 1 - 2/(1+exp2(C2L*z)), hardware rcp
  float e = __builtin_amdgcn_exp2f(z * C2L);
  float r = __builtin_amdgcn_rcpf(1.0f + e);
  return fmaf(r, -2.0f, 1.0f);
}

// ---------------- K0: layer0 + prep side tasks ----------------
// grid (128, 4), block 256. flat block id in [0,512):
//   [0,128)   -> B1c1 chunk,  [128,256) -> B1c2 chunk,  [256,288) -> out init.
__global__ __launch_bounds__(256) void kan_layer0(
    const float* __restrict__ x, const float* __restrict__ t,
    const float* __restrict__ W1, const float* __restrict__ B1,   // (64,2,8)
    const float* __restrict__ W2, const float* __restrict__ B2,   // (64,2,8),(64,2)
    const float* __restrict__ B1_1, const float* __restrict__ B1_2,
    const float* __restrict__ bout,
    float* __restrict__ hA,      // [64][8192] = C2L * h0
    float* __restrict__ B1c1, float* __restrict__ B1c2,
    float* __restrict__ out)     // (8192,) <- b_out
{
  const int tid  = threadIdx.x;
  const int lane = tid & 63;
  const int wave = __builtin_amdgcn_readfirstlane(tid >> 6);
  const int bx = blockIdx.x, by = blockIdx.y;
  const int flat = by * 128 + bx;

  if (flat < 128) {
    B1c1[flat * 256 + tid] = B1_1[flat * 256 + tid] * C2L;
  } else if (flat < 256) {
    B1c2[(flat - 128) * 256 + tid] = B1_2[(flat - 128) * 256 + tid] * C2L;
  } else if (flat < 288) {
    out[(flat - 256) * 256 + tid] = bout[0];
  }

  const int n  = bx * 64 + lane;
  const int j0 = by * 16 + wave * 4;
  const float hx = x[n], ht = t[n];
#pragma unroll
  for (int jj = 0; jj < 4; ++jj) {
    const int j = j0 + jj;
    float a0 = B2[j * 2 + 0];
    float a1 = B2[j * 2 + 1];
#pragma unroll
    for (int k = 0; k < 8; ++k) {
      float z0 = fmaf(hx, W1[j * 16 + k], B1[j * 16 + k]);
      a0 = fmaf(W2[j * 16 + k], tanh_hw(z0), a0);
      float z1 = fmaf(ht, W1[j * 16 + 8 + k], B1[j * 16 + 8 + k]);
      a1 = fmaf(W2[j * 16 + 8 + k], tanh_hw(z1), a1);
    }
    float y = a0 + a1;
    float e = __builtin_amdgcn_exp2f(y * C2L);
    float r = __builtin_amdgcn_rcpf(1.0f + e);
    hA[j * 8192 + n] = fmaf(r, -2.f * C2L, C2L);   // C2L * tanh(y)
  }
}

// ---------------- K1: layer1 (rcp_nr arm) ----------------
// grid (128, 16), block 256 (4 waves, 1 j per wave).
__global__ __launch_bounds__(256, 8) void kan_layer1(
    const float* __restrict__ hin,   // [64][8192] = C2L * h0
    const float* __restrict__ W1,    // (64,64,8)
    const float* __restrict__ B1c,   // (64,64,8) = C2L * B1
    const float* __restrict__ W2,    // (64,64,8)
    const float* __restrict__ B2,    // (64,64)
    float* __restrict__ hout)        // [64][8192] = C2L * h1
{
  __shared__ float hs[64][64];
  const int tid  = threadIdx.x;
  const int lane = tid & 63;
  const int wave = __builtin_amdgcn_readfirstlane(tid >> 6);
  const int n    = blockIdx.x * 64 + lane;

#pragma unroll
  for (int r = 0; r < 16; ++r) {
    const int i = r * 4 + wave;
    hs[i][lane] = hin[i * 8192 + n];
  }
  __syncthreads();

  const int j = blockIdx.y * 4 + wave;
  const float* __restrict__ w1p = W1  + j * 512;
  const float* __restrict__ b1p = B1c + j * 512;
  const float* __restrict__ w2p = W2  + j * 512;

  float sp = B2[j * 64 + lane];
  {
    const float4* w2v = (const float4*)w2p;
    float4 va = w2v[lane * 2 + 0];
    float4 vb = w2v[lane * 2 + 1];
    sp += (va.x + va.y) + (va.z + va.w) + (vb.x + vb.y) + (vb.z + vb.w);
  }
#pragma unroll
  for (int off = 32; off; off >>= 1) sp += __shfl_xor(sp, off);
  const float S = sp;

  float acc0 = 0.f, acc1 = 0.f, acc2 = 0.f, acc3 = 0.f;
#pragma unroll 2
  for (int i = 0; i < 64; ++i) {
    const float hc = hs[i][lane];
    const int base = i * 8;
#pragma unroll
    for (int k = 0; k < 8; k += 4) {
      float z0 = fmaf(hc, w1p[base + k + 0], b1p[base + k + 0]);
      float z1 = fmaf(hc, w1p[base + k + 1], b1p[base + k + 1]);
      float z2 = fmaf(hc, w1p[base + k + 2], b1p[base + k + 2]);
      float z3 = fmaf(hc, w1p[base + k + 3], b1p[base + k + 3]);
      float s0 = rcp_nr(1.0f + __builtin_amdgcn_exp2f(z0));
      float s1 = rcp_nr(1.0f + __builtin_amdgcn_exp2f(z1));
      float s2 = rcp_nr(1.0f + __builtin_amdgcn_exp2f(z2));
      float s3 = rcp_nr(1.0f + __builtin_amdgcn_exp2f(z3));
      acc0 = fmaf(w2p[base + k + 0], s0, acc0);
      acc1 = fmaf(w2p[base + k + 1], s1, acc1);
      acc2 = fmaf(w2p[base + k + 2], s2, acc2);
      acc3 = fmaf(w2p[base + k + 3], s3, acc3);
    }
  }

  const float y = S - 2.f * ((acc0 + acc1) + (acc2 + acc3));
  const float e = __builtin_amdgcn_exp2f(y * C2L);
  const float r = __builtin_amdgcn_rcpf(1.0f + e);
  hout[j * 8192 + n] = fmaf(r, -2.f * C2L, C2L);   // C2L * tanh(y)
}

// ---------------- K2: layer2 + head (v_rcp arm) ----------------
// grid (128, 16), block 256. Partial head sum -> one atomicAdd per point per block.
__global__ __launch_bounds__(256, 8) void kan_layer2(
    const float* __restrict__ hin,   // [64][8192] = C2L * h1
    const float* __restrict__ W1,    // (64,64,8)
    const float* __restrict__ B1c,   // (64,64,8) = C2L * B1
    const float* __restrict__ W2,    // (64,64,8)
    const float* __restrict__ B2,    // (64,64)
    const float* __restrict__ Wout,  // (1,64)
    float* __restrict__ out)         // (8192,) += partials
{
  __shared__ float hs[64][64];
  __shared__ float red[4][64];
  const int tid  = threadIdx.x;
  const int lane = tid & 63;
  const int wave = __builtin_amdgcn_readfirstlane(tid >> 6);
  const int n    = blockIdx.x * 64 + lane;

#pragma unroll
  for (int r = 0; r < 16; ++r) {
    const int i = r * 4 + wave;
    hs[i][lane] = hin[i * 8192 + n];
  }
  __syncthreads();

  const int j = blockIdx.y * 4 + wave;
  const float* __restrict__ w1p = W1  + j * 512;
  const float* __restrict__ b1p = B1c + j * 512;
  const float* __restrict__ w2p = W2  + j * 512;

  float sp = B2[j * 64 + lane];
  {
    const float4* w2v = (const float4*)w2p;
    float4 va = w2v[lane * 2 + 0];
    float4 vb = w2v[lane * 2 + 1];
    sp += (va.x + va.y) + (va.z + va.w) + (vb.x + vb.y) + (vb.z + vb.w);
  }
#pragma unroll
  for (int off = 32; off; off >>= 1) sp += __shfl_xor(sp, off);
  const float S = sp;

  float acc0 = 0.f, acc1 = 0.f, acc2 = 0.f, acc3 = 0.f;
#pragma unroll 2
  for (int i = 0; i < 64; ++i) {
    const float hc = hs[i][lane];
    const int base = i * 8;
#pragma unroll
    for (int k = 0; k < 8; k += 4) {
      float z0 = fmaf(hc, w1p[base + k + 0], b1p[base + k + 0]);
      float z1 = fmaf(hc, w1p[base + k + 1], b1p[base + k + 1]);
      float z2 = fmaf(hc, w1p[base + k + 2], b1p[base + k + 2]);
      float z3 = fmaf(hc, w1p[base + k + 3], b1p[base + k + 3]);
      float s0 = __builtin_amdgcn_rcpf(1.0f + __builtin_amdgcn_exp2f(z0));
      float s1 = __builtin_amdgcn_rcpf(1.0f + __builtin_amdgcn_exp2f(z1));
      float s2 = __builtin_amdgcn_rcpf(1.0f + __builtin_amdgcn_exp2f(z2));
      float s3 = __builtin_amdgcn_rcpf(1.0f + __builtin_amdgcn_exp2f(z3));
      acc0 = fmaf(w2p[base + k + 0], s0, acc0);
      acc1 = fmaf(w2p[base + k + 1], s1, acc1);
      acc2 = fmaf(w2p[base + k + 2], s2, acc2);
      acc3 = fmaf(w2p[base + k + 3], s3, acc3);
    }
  }

  const float y = S - 2.f * ((acc0 + acc1) + (acc2 + acc3));
  const float e = __builtin_amdgcn_exp2f(y * C2L);
  const float r = __builtin_amdgcn_rcpf(1.0f + e);
  const float h2 = fmaf(r, -2.f, 1.f);           // tanh(y)

  red[wave][lane] = h2 * Wout[j];
  __syncthreads();
  if (wave == 0) {
    const float pblk = (red[0][lane] + red[1][lane]) + (red[2][lane] + red[3][lane]);
    atomicAdd(&out[n], pblk);
  }
}

extern "C" void kernel_launch(void* const* d_in, const int* in_sizes, int n_in,
                              void* d_out, int out_size, void* d_ws, size_t ws_size,
                              hipStream_t stream) {
  const float* x    = (const float*)d_in[0];
  const float* t    = (const float*)d_in[1];
  const float* W1_0 = (const float*)d_in[2];
  const float* B1_0 = (const float*)d_in[3];
  const float* W2_0 = (const float*)d_in[4];
  const float* B2_0 = (const float*)d_in[5];
  const float* W1_1 = (const float*)d_in[6];
  const float* B1_1 = (const float*)d_in[7];
  const float* W2_1 = (const float*)d_in[8];
  const float* B2_1 = (const float*)d_in[9];
  const float* W1_2 = (const float*)d_in[10];
  const float* B1_2 = (const float*)d_in[11];
  const float* W2_2 = (const float*)d_in[12];
  const float* B2_2 = (const float*)d_in[13];
  const float* Wout = (const float*)d_in[14];
  const float* bout = (const float*)d_in[15];
  float* out = (float*)d_out;

  float* hA   = (float*)d_ws;          // [64][8192] = 2 MB
  float* hB   = hA + 64 * 8192;        // [64][8192] = 2 MB
  float* B1c1 = hB + 64 * 8192;        // 32768 floats
  float* B1c2 = B1c1 + 32768;          // 32768 floats

  kan_layer0<<<dim3(128, 4), 256, 0, stream>>>(
      x, t, W1_0, B1_0, W2_0, B2_0, B1_1, B1_2, bout, hA, B1c1, B1c2, out);
  kan_layer1<<<dim3(128, 16), 256, 0, stream>>>(hA, W1_1, B1c1, W2_1, B2_1, hB);
  kan_layer2<<<dim3(128, 16), 256, 0, stream>>>(hB, W1_2, B1c2, W2_2, B2_2, Wout, out);
}